// Round 9
// baseline (625.427 us; speedup 1.0000x reference)
//
#include <hip/hip_runtime.h>
#include <math.h>
#include <stdint.h>

// Problem: M=131072 rows, N=4000 verts, D=16. 32-col tiles: 125 real tiles,
// padded to 128 (pad cols carry ysq=65536 -> never win).
#define M_ROWS   131072
#define N_VERTS  4000
#define D_DIM    16
#define N_COLS_PAD 4096
#define N_TILES  128                  // 32 cols per tile
#define TILE_B   2048                 // Yh (64 lanes x 16B) + Yl (same)
#define CHUNK_T  8                    // tiles per LDS chunk
#define CHUNK_B  (CHUNK_T * TILE_B)   // 16384 B
#define N_CHUNKS (N_TILES / CHUNK_T)  // 16

// Scores biased +128 -> provably positive -> positive-float bits monotone as
// u32 -> min_u32 = fused best+argmin on keys = (score_bits & ~0xFF) | tile.
#define SCORE_BIAS 128.0f
// Error budget: key truncation <= 7.8e-3, arithmetic (dropped al*yl ~5e-4,
// fp32 accum ~2e-4, ysq f32 ~1e-7) <= ~1e-3 -> bound ~1.1e-2 < TIE_EPS.
#define TIE_EPS 0.02f

// d_ws layout (bytes):
//   [0      .. 262144)  yfrag : N_TILES x 2048 B (Yh | Yl fragments)
//   [262144 .. 278528)  ysq   : 4096 floats (bias baked in; pads 65536)
//   [278528 .. 278532)  cnt
//   [278592 .. ...   )  list  : ambiguous row indices
#define WS_YSQ_OFF  (N_TILES * TILE_B)
#define WS_CNT_OFF  (WS_YSQ_OFF + 16384)
#define WS_LIST_OFF (WS_CNT_OFF + 64)

typedef float f32x16 __attribute__((ext_vector_type(16)));
typedef short s16x8 __attribute__((ext_vector_type(8)));

__device__ __forceinline__ unsigned short f32_to_bf16_rne(float f) {
    unsigned int u = __float_as_uint(f);
    u = (u + 0x7fffu + ((u >> 16) & 1u)) >> 16;
    return (unsigned short)u;
}
__device__ __forceinline__ float bf16_to_f32(unsigned short h) {
    return __uint_as_float(((unsigned int)h) << 16);
}
__device__ __forceinline__ uint32_t umin32(uint32_t a, uint32_t b) { return a < b ? a : b; }
__device__ __forceinline__ uint32_t umax32(uint32_t a, uint32_t b) { return a > b ? a : b; }

// ---------------------------------------------------------------------------
// Kernel 1: pack Y fragments for mfma_f32_32x32x16_bf16 B-layout:
// B[k][n]: lane l holds n = T*32 + (l&31), k = (l>>5)*8 + j (j=0..7).
// Yh = bf16 hi parts, Yl = bf16 lo parts of y (pads = 0). Also ysq[n] =
// ||y||^2 + SCORE_BIAS as f32 (pads 65536), and zero the atomic cnt.
// 8192 threads = 128 tiles x 64 lanes; first 4096 also do ysq.
// ---------------------------------------------------------------------------
__global__ void pack_y_kernel(const float* __restrict__ verts,
                              char* __restrict__ yfrag,
                              float* __restrict__ ysq,
                              int* __restrict__ cnt) {
    const int tid = blockIdx.x * blockDim.x + threadIdx.x;   // 0..8191
    if (tid == 0) *cnt = 0;

    if (tid < N_COLS_PAD) {
        float ys;
        if (tid < N_VERTS) {
            const float* y = verts + (size_t)tid * D_DIM;
            ys = SCORE_BIAS;
#pragma unroll
            for (int d = 0; d < D_DIM; ++d) ys = fmaf(y[d], y[d], ys);
        } else {
            ys = 65536.f;   // dominates every real score
        }
        ysq[tid] = ys;
    }

    const int T = tid >> 6;
    const int l = tid & 63;
    const int h = l >> 5;
    const int cidx = l & 31;
    const int n = T * 32 + cidx;

    float v[8];
    if (n < N_VERTS) {
        const float* y = verts + (size_t)n * D_DIM + h * 8;
#pragma unroll
        for (int j = 0; j < 8; ++j) v[j] = y[j];
    } else {
#pragma unroll
        for (int j = 0; j < 8; ++j) v[j] = 0.f;
    }
    s16x8 bh, bl;
#pragma unroll
    for (int j = 0; j < 8; ++j) {
        const unsigned short hh = f32_to_bf16_rne(v[j]);
        bh[j] = (short)hh;
        bl[j] = (short)f32_to_bf16_rne(v[j] - bf16_to_f32(hh));
    }
    char* p = yfrag + (size_t)T * TILE_B + l * 16;
    *(s16x8*)p = bh;
    *(s16x8*)(p + 1024) = bl;
}

// ---------------------------------------------------------------------------
// Kernel 2 (MFMA screen, 32x32x16): 512 thr = 8 waves; wave = 32 rows;
// block = 256 rows; grid = 512 (2 blocks/CU, one full round). Per 32-col
// tile: 2 ds_read_b128 + 1 ds_read_b32 serve 3 MFMAs -> 1024 scores (4x
// less LDS traffic per score than the 16x16 path, which was the R5 binder).
// a = -2x split bf16: acc = ah*yh + al*yh + ah*yl (al*yl dropped, <=5e-4).
// score = acc[r] + ysq[col] (one scalar per lane: all 16 regs share col).
// Select: key=(bits&~0xFF)|tile; min_u32=best+argmin, max+min=second.
// Epilogue: 5-step col-butterfly (cross-lane, carries col), 2 writer lanes.
// ---------------------------------------------------------------------------
__global__ __launch_bounds__(512, 4) void mfma_screen_kernel(
    const float* __restrict__ x_all,    // (M,16)
    const float* __restrict__ colors,   // (N,3)
    const char* __restrict__ yfrag,     // N_TILES x 2048 B
    const float* __restrict__ ysqg,     // 4096 floats
    float* __restrict__ out,            // (M,3)
    int* __restrict__ cnt,
    int* __restrict__ list,
    int list_cap)
{
    __shared__ __align__(16) char  s_buf[2 * CHUNK_B];   // 32 KB
    __shared__ __align__(16) float s_ysq[N_COLS_PAD];    // 16 KB

    const int tid  = threadIdx.x;
    const int wave = tid >> 6;
    const int lane = tid & 63;
    const int h = lane >> 5;           // k-half
    const int cidx = lane & 31;        // col within tile == m within wave-rows
    const int waveRow = blockIdx.x * 256 + wave * 32;

    // --- A fragments: A[m = lane&31][k = h*8+j] of a = -2x; split bf16.
    const float* xr = x_all + (size_t)(waveRow + cidx) * D_DIM + h * 8;
    const float4 xa = *(const float4*)xr;
    const float4 xb = *(const float4*)(xr + 4);
    const float xv[8] = {xa.x, xa.y, xa.z, xa.w, xb.x, xb.y, xb.z, xb.w};
    s16x8 ah, al;
#pragma unroll
    for (int j = 0; j < 8; ++j) {
        const float a = -2.0f * xv[j];
        const unsigned short hh = f32_to_bf16_rne(a);
        ah[j] = (short)hh;
        al[j] = (short)f32_to_bf16_rne(a - bf16_to_f32(hh));
    }

    // --- Stage ysq once (1024 int4; 2 per thread).
    {
        const int4* g = (const int4*)ysqg;
        int4* s = (int4*)s_ysq;
        s[tid] = g[tid];
        s[tid + 512] = g[tid + 512];
    }
    // --- Prologue: chunk 0 -> buf0 (16 KB = 1024 int4; 2 per thread).
    const int4* gy = (const int4*)yfrag;
    int4 p0 = gy[tid];
    int4 p1 = gy[tid + 512];
    {
        int4* s = (int4*)s_buf;
        s[tid] = p0;
        s[tid + 512] = p1;
    }

    const f32x16 zero16 = {0.f,0.f,0.f,0.f, 0.f,0.f,0.f,0.f,
                           0.f,0.f,0.f,0.f, 0.f,0.f,0.f,0.f};
    uint32_t best[16], second[16];
#pragma unroll
    for (int r = 0; r < 16; ++r) { best[r] = 0xFFFFFFFFu; second[r] = 0xFFFFFFFFu; }

    for (int ch = 0; ch < N_CHUNKS; ++ch) {
        if (ch + 1 < N_CHUNKS) {       // reg-prefetch next chunk
            const int4* g = gy + (ch + 1) * (CHUNK_B / 16);
            p0 = g[tid];
            p1 = g[tid + 512];
        }
        __syncthreads();               // buf[ch&1] writes visible

        const char* bufc = s_buf + (ch & 1) * CHUNK_B + lane * 16;
        const int tbase = ch * CHUNK_T;
#pragma unroll
        for (int t = 0; t < CHUNK_T; ++t) {
            const s16x8 bh = *(const s16x8*)(bufc + t * TILE_B);
            const s16x8 bl = *(const s16x8*)(bufc + t * TILE_B + 1024);
            const float ysn = s_ysq[(tbase + t) * 32 + cidx];
            f32x16 acc = __builtin_amdgcn_mfma_f32_32x32x16_bf16(ah, bh, zero16, 0, 0, 0);
            acc = __builtin_amdgcn_mfma_f32_32x32x16_bf16(al, bh, acc, 0, 0, 0);
            acc = __builtin_amdgcn_mfma_f32_32x32x16_bf16(ah, bl, acc, 0, 0, 0);
            const uint32_t tcur = (uint32_t)(tbase + t);
#pragma unroll
            for (int r = 0; r < 16; ++r) {
                const float s = acc[r] + ysn;
                const uint32_t kb = (__float_as_uint(s) & 0xFFFFFF00u) | tcur;
                const uint32_t ob = best[r];
                second[r] = umin32(second[r], umax32(ob, kb));
                best[r]   = umin32(ob, kb);
            }
        }
        if (ch + 1 < N_CHUNKS) {       // store prefetched chunk to other buf
            int4* s = (int4*)(s_buf + ((ch + 1) & 1) * CHUNK_B);
            s[tid] = p0;
            s[tid + 512] = p1;
        }
    }

    // --- Cross-col butterfly (xor 1..16 stays within each 32-lane half).
    // Carries col explicitly; equal keys (same tile+trunc score) -> min col,
    // and such ties are always flagged ambiguous (gap 0 <= eps) anyway.
    uint32_t col[16];
#pragma unroll
    for (int r = 0; r < 16; ++r) col[r] = (uint32_t)cidx;
#pragma unroll
    for (int off = 1; off < 32; off <<= 1) {
#pragma unroll
        for (int r = 0; r < 16; ++r) {
            const uint32_t ob = __shfl_xor(best[r], off, 64);
            const uint32_t oc = __shfl_xor(col[r], off, 64);
            const uint32_t os = __shfl_xor(second[r], off, 64);
            second[r] = umin32(umin32(second[r], os), umax32(best[r], ob));
            if (ob < best[r]) { best[r] = ob; col[r] = oc; }
            else if (ob == best[r]) col[r] = umin32(col[r], oc);
        }
    }

    // --- Writers: lanes 0 and 32 finalize their half's 16 rows.
    if (cidx == 0) {
#pragma unroll
        for (int r = 0; r < 16; ++r) {
            const int row = (r & 3) + 8 * (r >> 2) + 4 * h;  // C/D row map
            const int m = waveRow + row;
            const int n = (int)(best[r] & 0xFFu) * 32 + (int)col[r];
            const float s1 = __uint_as_float(best[r] & 0xFFFFFF00u);
            const float s2 = __uint_as_float(second[r] & 0xFFFFFF00u);
            bool amb = (s2 - s1 <= TIE_EPS);
            if (amb) {
                const int pos = atomicAdd(cnt, 1);
                if (pos < list_cap) list[pos] = m;
                else amb = false;               // overflow: keep winner
            }
            if (!amb) {
                const float* cc = colors + (size_t)n * 3;
                float* o = out + (size_t)m * 3;
                o[0] = cc[0];
                o[1] = cc[1];
                o[2] = cc[2];
            }
        }
    }
}

// ---------------------------------------------------------------------------
// Kernel 3 (rescan): R5's verified-fast shape — one wave per ambiguous row,
// lane-per-vert (each lane reads its own contiguous 64 B row: the wave-iter
// touches 4 KB contiguous, line-coalesced), fp64 exact, NO shuffles in the
// hot loop. Lexicographic (s, idx) butterfly = np.argmin first-index.
// ---------------------------------------------------------------------------
__global__ __launch_bounds__(256) void rescan_kernel(
    const float* __restrict__ x_all,
    const float* __restrict__ colors,
    const float* __restrict__ verts,
    const int* __restrict__ cnt,
    const int* __restrict__ list,
    int list_cap,
    float* __restrict__ out)
{
    const int wid  = blockIdx.x * 4 + (threadIdx.x >> 6);
    const int lane = threadIdx.x & 63;
    const int nWaves = gridDim.x * 4;

    int ccount = *cnt;
    if (ccount > list_cap) ccount = list_cap;

    for (int rr = wid; rr < ccount; rr += nWaves) {
        const int m = list[rr];
        double bx[D_DIM];
#pragma unroll
        for (int d = 0; d < D_DIM; ++d)
            bx[d] = (double)x_all[(size_t)m * D_DIM + d];

        double best = INFINITY;
        int bi = 0x7fffffff;
#pragma unroll 2
        for (int n = lane; n < N_VERTS; n += 64) {
            const float* y = verts + (size_t)n * D_DIM;
            double dot = 0.0, ys = 0.0;
#pragma unroll
            for (int d = 0; d < D_DIM; ++d) {
                const double yd = (double)y[d];
                dot = fma(bx[d], yd, dot);
                ys  = fma(yd, yd, ys);
            }
            const double s = ys - 2.0 * dot;
            if (s < best || (s == best && n < bi)) { best = s; bi = n; }
        }
#pragma unroll
        for (int off = 32; off > 0; off >>= 1) {
            const double ob = __shfl_xor(best, off, 64);
            const int    oi = __shfl_xor(bi, off, 64);
            if (ob < best || (ob == best && oi < bi)) { best = ob; bi = oi; }
        }
        if (lane == 0) {
            const float* cc = colors + (size_t)bi * 3;
            float* o = out + (size_t)m * 3;
            o[0] = cc[0];
            o[1] = cc[1];
            o[2] = cc[2];
        }
    }
}

// ---------------------------------------------------------------------------
extern "C" void kernel_launch(void* const* d_in, const int* in_sizes, int n_in,
                              void* d_out, int out_size, void* d_ws, size_t ws_size,
                              hipStream_t stream) {
    const float* cse_embedding       = (const float*)d_in[0]; // (M,16)
    const float* verts_colors        = (const float*)d_in[1]; // (N,3)
    const float* verts_cse_embedding = (const float*)d_in[2]; // (N,16)
    float* out = (float*)d_out;                               // (M,3)

    char* ws = (char*)d_ws;
    char*  yfrag = ws;
    float* ysq   = (float*)(ws + WS_YSQ_OFF);
    int*   cnt   = (int*)(ws + WS_CNT_OFF);
    int*   list  = (int*)(ws + WS_LIST_OFF);
    int list_cap = (int)((ws_size > WS_LIST_OFF)
                         ? ((ws_size - WS_LIST_OFF) / sizeof(int)) : 0);
    if (list_cap > M_ROWS) list_cap = M_ROWS;

    pack_y_kernel<<<(N_TILES * 64) / 256, 256, 0, stream>>>(
        verts_cse_embedding, yfrag, ysq, cnt);

    mfma_screen_kernel<<<M_ROWS / 256, 512, 0, stream>>>(
        cse_embedding, verts_colors, yfrag, ysq, out, cnt, list, list_cap);

    rescan_kernel<<<512, 256, 0, stream>>>(
        cse_embedding, verts_colors, verts_cse_embedding, cnt, list,
        list_cap, out);
}

// Round 10
// 500.001 us; speedup vs baseline: 1.2509x; 1.2509x over previous
//
#include <hip/hip_runtime.h>
#include <math.h>
#include <stdint.h>

// Problem: M=131072 rows, N=4000 verts, D=16. 250 real 16-col tiles, padded
// to 256 tiles (pad cols carry ysq=1e30 -> never win).
#define M_ROWS   131072
#define N_VERTS  4000
#define D_DIM    16
#define N_TILES_REAL 250
#define N_TILES  256
#define CHUNK_T  16                     // tiles per LDS chunk
#define FRAG_B   (CHUNK_T * 1024)       // 16384 B of fragments per chunk
#define CH_B     (FRAG_B + 1024)        // + 256 f32 ysq = 17408 B per chunk
#define N_CHUNKS (N_TILES / CHUNK_T)    // 16

// Scores biased +128 -> provably positive -> positive-float bits monotone as
// u32 -> min_u32 = fused best+argmin on keys = (score_bits & ~0xFF) | tile.
#define SCORE_BIAS 128.0f
// Error budget: key truncation granule <= 7.8e-3 (scores+bias < 512);
// split-bf16 arithmetic exact to ~1e-3 (A1=[ah|ah],A2=[al|al],B=[yh|yl]
// gives full (ah+al)(yh+yl)). Winner can be wrong only if true gap <=
// granule + 2*arith ~ 9.8e-3; trunc-gap overestimates by <= granule ->
// TIE_EPS = 0.02 flags all dangerous rows.
#define TIE_EPS 0.02f

// d_ws layout (bytes):
//   [0      .. 278528)  yfrag : 16 chunks x 17408 B
//                               (16x1024 B fragments | 256 f32 ysq)
//   [278528 .. 278532)  cnt
//   [278592 .. ...   )  list  : ambiguous row indices
#define WS_CNT_OFF   (N_CHUNKS * CH_B)
#define WS_LIST_OFF  (WS_CNT_OFF + 64)

typedef float f32x4 __attribute__((ext_vector_type(4)));
typedef short s16x8 __attribute__((ext_vector_type(8)));

__device__ __forceinline__ unsigned short f32_to_bf16_rne(float f) {
    unsigned int u = __float_as_uint(f);
    u = (u + 0x7fffu + ((u >> 16) & 1u)) >> 16;
    return (unsigned short)u;
}
__device__ __forceinline__ float bf16_to_f32(unsigned short h) {
    return __uint_as_float(((unsigned int)h) << 16);
}
__device__ __forceinline__ uint32_t umin32(uint32_t a, uint32_t b) { return a < b ? a : b; }
__device__ __forceinline__ uint32_t umax32(uint32_t a, uint32_t b) { return a > b ? a : b; }

// ---------------------------------------------------------------------------
// Kernel 1: pack Y into chunk-interleaved fragments + ysq (round-5 verified
// fragment scheme). Per (tile T, lane l): q=l>>4, c=l&15, n=T*16+c.
//   B[j] = (q<2 ? yh : yl)[(q&1)*8 + j]   (B = [yh(k0..15) | yl(k16..31)])
// Fragment at chunk(T>>4)*17408 + (T&15)*1024 + l*16.
// ysq[n] = ||y||^2 + SCORE_BIAS (f32) at chunk(n>>8)*17408 + 16384 + (n&255)*4;
// pads (n >= 4000): y=0, ysq=1e30 (never wins). Also zero the atomic cnt.
// ---------------------------------------------------------------------------
__global__ void pack_y_kernel(const float* __restrict__ verts,
                              char* __restrict__ yfrag,
                              int* __restrict__ cnt) {
    const int tid = blockIdx.x * blockDim.x + threadIdx.x;   // 0..16383
    if (tid == 0) *cnt = 0;

    const int T = tid >> 6;
    const int l = tid & 63;
    const int q = l >> 4;
    const int c = l & 15;
    const int n = T * 16 + c;

    float yv[16];
    if (n < N_VERTS) {
        const float* y = verts + (size_t)n * D_DIM;
#pragma unroll
        for (int d = 0; d < D_DIM; ++d) yv[d] = y[d];
    } else {
#pragma unroll
        for (int d = 0; d < D_DIM; ++d) yv[d] = 0.f;
    }

    const int half = (q & 1) * 8;
    s16x8 b;
#pragma unroll
    for (int j = 0; j < 8; ++j) {
        const float v = yv[half + j];
        const unsigned short hh = f32_to_bf16_rne(v);
        b[j] = (short)((q < 2) ? hh : f32_to_bf16_rne(v - bf16_to_f32(hh)));
    }
    char* p = yfrag + (size_t)(T >> 4) * CH_B + (T & 15) * 1024 + l * 16;
    *(s16x8*)p = b;

    // ysq: first 4096 threads, one col each.
    if (tid < N_TILES * 16) {
        float ys;
        if (tid < N_VERTS) {
            const float* y = verts + (size_t)tid * D_DIM;
            ys = SCORE_BIAS;
#pragma unroll
            for (int d = 0; d < D_DIM; ++d) ys = fmaf(y[d], y[d], ys);
        } else {
            ys = 1e30f;   // pad col: never best, never real second
        }
        *(float*)(yfrag + (size_t)(tid >> 8) * CH_B + FRAG_B + (tid & 255) * 4) = ys;
    }
}

// ---------------------------------------------------------------------------
// Kernel 2 (MFMA screen): round-5's 116 us structure VERBATIM except ysq is
// staged inside each chunk (34 KB LDS total -> 4 blocks/CU = 32 waves/CU;
// round-5's separate 16 KB s_ysq capped it at 51% occupancy).
// 512 thr = 8 waves, wave = 16 rows, VGPR ~40 (the only shape that hasn't
// spilled; R7/R9 fat-state waves thrashed scratch at GB scale).
// Per tile: 1 ds_read_b128 (B=[yh|yl]) + 1 ds_read_b32 (ysq) + 2 MFMAs
// (A1=[ah|ah], A2=[al|al] -> exact (ah+al)(yh+yl)) + 16 select VALU.
// Select: key=(bits&~0xFF)|tile; min_u32=best+argmin, max+min=second.
// ---------------------------------------------------------------------------
__global__ __launch_bounds__(512, 8) void mfma_screen_kernel(
    const float* __restrict__ x_all,    // (M,16)
    const float* __restrict__ colors,   // (N,3)
    const char* __restrict__ yfrag,     // 16 chunks x 17408 B
    float* __restrict__ out,            // (M,3)
    int* __restrict__ cnt,
    int* __restrict__ list,
    int list_cap)
{
    __shared__ __align__(16) char s_buf[2 * CH_B];   // 34816 B (reused for reduce)

    const int tid  = threadIdx.x;
    const int wave = tid >> 6;
    const int lane = tid & 63;
    const int q = lane >> 4;
    const int c = lane & 15;
    const int rowBase = blockIdx.x * 128 + wave * 16;

    // --- A fragments: A1 = [ah|ah], A2 = [al|al] of a = -2x (half = q&1).
    const float* xr = x_all + (size_t)(rowBase + c) * D_DIM + (q & 1) * 8;
    const float4 xa = *(const float4*)xr;
    const float4 xb = *(const float4*)(xr + 4);
    const float xv[8] = {xa.x, xa.y, xa.z, xa.w, xb.x, xb.y, xb.z, xb.w};
    s16x8 a1, a2;
#pragma unroll
    for (int j = 0; j < 8; ++j) {
        const float a = -2.0f * xv[j];
        const unsigned short hh = f32_to_bf16_rne(a);
        a1[j] = (short)hh;
        a2[j] = (short)f32_to_bf16_rne(a - bf16_to_f32(hh));
    }

    uint32_t best[4]   = {0xFFFFFFFFu, 0xFFFFFFFFu, 0xFFFFFFFFu, 0xFFFFFFFFu};
    uint32_t second[4] = {0xFFFFFFFFu, 0xFFFFFFFFu, 0xFFFFFFFFu, 0xFFFFFFFFu};

    // --- Prologue: chunk 0 -> buf0. 1088 int4/chunk: 512 thr x 2 (frags)
    // + first 64 thr x 1 (ysq block).
    const int4* gy = (const int4*)yfrag;
    int4 p0 = gy[tid];
    int4 p1 = gy[tid + 512];
    int4 pq;
    if (tid < 64) pq = gy[tid + 1024];
    {
        int4* s = (int4*)s_buf;
        s[tid] = p0;
        s[tid + 512] = p1;
        if (tid < 64) s[tid + 1024] = pq;
    }

    for (int ch = 0; ch < N_CHUNKS; ++ch) {
        // Reg-prefetch next chunk (overlaps the compute below).
        if (ch + 1 < N_CHUNKS) {
            const int4* g = gy + (ch + 1) * (CH_B / 16);
            p0 = g[tid];
            p1 = g[tid + 512];
            if (tid < 64) pq = g[tid + 1024];
        }
        __syncthreads();   // buf[ch&1] writes (prev tail / prologue) visible

        const char* bufc = s_buf + (ch & 1) * CH_B;
        const char* fragc = bufc + lane * 16;
        const float* ysc = (const float*)(bufc + FRAG_B) + c;
#pragma unroll
        for (int t = 0; t < CHUNK_T; ++t) {
            const s16x8 bf = *(const s16x8*)(fragc + t * 1024);
            const float ys = ysc[t * 16];          // 16 words, 4-way bcast: free
            f32x4 acc = {ys, ys, ys, ys};
            acc = __builtin_amdgcn_mfma_f32_16x16x32_bf16(a1, bf, acc, 0, 0, 0);
            acc = __builtin_amdgcn_mfma_f32_16x16x32_bf16(a2, bf, acc, 0, 0, 0);
            const uint32_t tcur = (uint32_t)(ch * CHUNK_T + t);
#pragma unroll
            for (int r = 0; r < 4; ++r) {
                const uint32_t kb = (__float_as_uint(acc[r]) & 0xFFFFFF00u) | tcur;
                const uint32_t ob = best[r];
                second[r] = umin32(second[r], umax32(ob, kb));
                best[r]   = umin32(ob, kb);
            }
        }
        // Store prefetched chunk to the other buffer (its readers were fenced
        // by this iteration's top barrier).
        if (ch + 1 < N_CHUNKS) {
            int4* s = (int4*)(s_buf + ((ch + 1) & 1) * CH_B);
            s[tid] = p0;
            s[tid + 512] = p1;
            if (tid < 64) s[tid + 1024] = pq;
        }
    }

    // --- Cross-c reduce via LDS (round-5 epilogue). 8 KB + 8 KB in s_buf.
    __syncthreads();
    uint32_t* s_red  = (uint32_t*)s_buf;
    uint32_t* s_red2 = (uint32_t*)(s_buf + 8192);
#pragma unroll
    for (int r = 0; r < 4; ++r) {
        const int row = q * 4 + r;            // C/D: row = (lane>>4)*4 + reg
        s_red [wave * 256 + row * 16 + c] = best[r];
        s_red2[wave * 256 + row * 16 + c] = second[r];
    }
    __syncthreads();

    if (lane < 16) {
        const int row = lane;
        uint32_t b1 = 0xFFFFFFFFu, b2 = 0xFFFFFFFFu, smin = 0xFFFFFFFFu;
        int cwin = 0;
#pragma unroll
        for (int cc = 0; cc < 16; ++cc) {
            const uint32_t k  = s_red [wave * 256 + row * 16 + cc];
            const uint32_t s2 = s_red2[wave * 256 + row * 16 + cc];
            smin = umin32(smin, s2);
            cwin = (k < b1) ? cc : cwin;      // strict <: earliest c on ties
            b2 = umin32(b2, umax32(b1, k));   // 2nd-min of bests
            b1 = umin32(b1, k);
        }
        const uint32_t secondAll = umin32(smin, b2);
        const float s1 = __uint_as_float(b1 & 0xFFFFFF00u);
        const float s2 = __uint_as_float(secondAll & 0xFFFFFF00u);
        const int n = (int)(b1 & 0xFFu) * 16 + cwin;
        const int m = rowBase + row;

        bool amb = (s2 - s1 <= TIE_EPS);
        if (amb) {
            const int pos = atomicAdd(cnt, 1);
            if (pos < list_cap) list[pos] = m;
            else amb = false;                 // overflow: keep screened winner
        }
        if (!amb) {
            const float* cc2 = colors + (size_t)n * 3;
            float* o = out + (size_t)m * 3;
            o[0] = cc2[0];
            o[1] = cc2[1];
            o[2] = cc2[2];
        }
    }
}

// ---------------------------------------------------------------------------
// Kernel 3 (rescan): one wave per ambiguous row, lane-per-vert (wave-iter
// touches 4 KB contiguous; per-lane 64 B row served by one line in L1),
// fp64 exact (= f64 numpy ref), NO shuffles in the hot loop.
// Lexicographic (s, idx) butterfly = np.argmin first-index semantics.
// ---------------------------------------------------------------------------
__global__ __launch_bounds__(256) void rescan_kernel(
    const float* __restrict__ x_all,
    const float* __restrict__ colors,
    const float* __restrict__ verts,
    const int* __restrict__ cnt,
    const int* __restrict__ list,
    int list_cap,
    float* __restrict__ out)
{
    const int wid  = blockIdx.x * 4 + (threadIdx.x >> 6);
    const int lane = threadIdx.x & 63;
    const int nWaves = gridDim.x * 4;

    int ccount = *cnt;
    if (ccount > list_cap) ccount = list_cap;

    for (int rr = wid; rr < ccount; rr += nWaves) {
        const int m = list[rr];
        double bx[D_DIM];
#pragma unroll
        for (int d = 0; d < D_DIM; ++d)
            bx[d] = (double)x_all[(size_t)m * D_DIM + d];

        double best = INFINITY;
        int bi = 0x7fffffff;
#pragma unroll 2
        for (int n = lane; n < N_VERTS; n += 64) {
            const float* y = verts + (size_t)n * D_DIM;
            double dot = 0.0, ys = 0.0;
#pragma unroll
            for (int d = 0; d < D_DIM; ++d) {
                const double yd = (double)y[d];
                dot = fma(bx[d], yd, dot);
                ys  = fma(yd, yd, ys);
            }
            const double s = ys - 2.0 * dot;
            if (s < best || (s == best && n < bi)) { best = s; bi = n; }
        }
#pragma unroll
        for (int off = 32; off > 0; off >>= 1) {
            const double ob = __shfl_xor(best, off, 64);
            const int    oi = __shfl_xor(bi, off, 64);
            if (ob < best || (ob == best && oi < bi)) { best = ob; bi = oi; }
        }
        if (lane == 0) {
            const float* cc = colors + (size_t)bi * 3;
            float* o = out + (size_t)m * 3;
            o[0] = cc[0];
            o[1] = cc[1];
            o[2] = cc[2];
        }
    }
}

// ---------------------------------------------------------------------------
extern "C" void kernel_launch(void* const* d_in, const int* in_sizes, int n_in,
                              void* d_out, int out_size, void* d_ws, size_t ws_size,
                              hipStream_t stream) {
    const float* cse_embedding       = (const float*)d_in[0]; // (M,16)
    const float* verts_colors        = (const float*)d_in[1]; // (N,3)
    const float* verts_cse_embedding = (const float*)d_in[2]; // (N,16)
    float* out = (float*)d_out;                               // (M,3)

    char* ws = (char*)d_ws;
    char* yfrag = ws;
    int*  cnt   = (int*)(ws + WS_CNT_OFF);
    int*  list  = (int*)(ws + WS_LIST_OFF);
    int list_cap = (int)((ws_size > WS_LIST_OFF)
                         ? ((ws_size - WS_LIST_OFF) / sizeof(int)) : 0);
    if (list_cap > M_ROWS) list_cap = M_ROWS;

    pack_y_kernel<<<(N_TILES * 64) / 256, 256, 0, stream>>>(
        verts_cse_embedding, yfrag, cnt);

    mfma_screen_kernel<<<M_ROWS / 128, 512, 0, stream>>>(
        cse_embedding, verts_colors, yfrag, out, cnt, list, list_cap);

    rescan_kernel<<<1024, 256, 0, stream>>>(
        cse_embedding, verts_colors, verts_cse_embedding, cnt, list,
        list_cap, out);
}